// Round 1
// baseline (223.007 us; speedup 1.0000x reference)
//
#include <hip/hip_runtime.h>
#include <math.h>

#define BB 4
#define NN 4096
#define DD 8
#define KK 64
#define REP_PB 64   // blocks per batch for repulsion kernel

// ---------------- kernel 1: per-batch stats (one block per batch) -------------
// Computes: first_cp[K] (segment min), counts[K], cp index compaction,
// bce partial sums -> bce[b], pos[b]; then d2 segment sums -> seg_sum[b][K].
// Also zero-inits rep accumulator (ws is poisoned before every call).
__global__ __launch_bounds__(1024) void kstats(
    const float* __restrict__ beta, const float* __restrict__ embed,
    const int* __restrict__ slice_id, const int* __restrict__ is_cp,
    int* __restrict__ g_first, int* __restrict__ g_counts,
    int* __restrict__ g_cpcount, int* __restrict__ g_cpidx,
    float* __restrict__ g_posf, float* __restrict__ g_bce,
    float* __restrict__ g_rep, float* __restrict__ g_seg)
{
    const int b = blockIdx.x;
    const int t = threadIdx.x;

    __shared__ int   s_first[KK];
    __shared__ int   s_counts[KK];
    __shared__ float s_seg[KK];
    __shared__ int   s_cpn;
    __shared__ float r1[16], r2[16], r3[16];

    if (t < KK) { s_first[t] = NN; s_counts[t] = 0; s_seg[t] = 0.f; }
    if (t == 0) s_cpn = 0;
    __syncthreads();

    const float* beta_b = beta + (size_t)b * NN;
    const int*   sid_b  = slice_id + (size_t)b * NN;
    const int*   cp_b   = is_cp + (size_t)b * NN;
    const float* emb_b  = embed + (size_t)b * NN * DD;

    float a1 = 0.f;   // sum over y==1 of softplus(-beta)
    float a2 = 0.f;   // sum over y==0 of softplus(beta)
    int   posl = 0;

    #pragma unroll
    for (int k = 0; k < NN / 1024; ++k) {
        int i = t + k * 1024;
        int sid = sid_b[i];
        int cp  = cp_b[i];
        float bt = beta_b[i];
        float spn = log1pf(__expf(-fabsf(bt)));  // log(1+e^{-|x|})
        if (cp == 1) {
            a1 += spn + fmaxf(-bt, 0.f);   // softplus(-bt)
            posl += 1;
            atomicMin(&s_first[sid], i);
            int slot = atomicAdd(&s_cpn, 1);
            g_cpidx[b * NN + slot] = i;
        } else {
            a2 += spn + fmaxf(bt, 0.f);    // softplus(bt)
        }
        atomicAdd(&s_counts[sid], 1);
    }

    // block reduction of a1, a2, pos
    float posf = (float)posl;
    #pragma unroll
    for (int o = 32; o > 0; o >>= 1) {
        a1   += __shfl_down(a1, o, 64);
        a2   += __shfl_down(a2, o, 64);
        posf += __shfl_down(posf, o, 64);
    }
    int wid = t >> 6, lane = t & 63;
    if (lane == 0) { r1[wid] = a1; r2[wid] = a2; r3[wid] = posf; }
    __syncthreads();   // also fences s_first/s_counts/s_cpn atomics

    if (t == 0) {
        float A1 = 0.f, A2 = 0.f, P = 0.f;
        #pragma unroll
        for (int w = 0; w < 16; ++w) { A1 += r1[w]; A2 += r2[w]; P += r3[w]; }
        float neg = (float)NN - P;
        float pw  = neg / (P + 1e-6f);
        g_bce[b]  = (pw * A1 + A2) / (float)NN;
        g_posf[b] = P;
        g_rep[b]  = 0.f;
        g_cpcount[b] = s_cpn;
    }

    // phase 2: d2 vs first-cp of own segment, segment-summed in LDS
    #pragma unroll
    for (int k = 0; k < NN / 1024; ++k) {
        int i = t + k * 1024;
        int sid = sid_b[i];
        int f = s_first[sid];
        if (f > NN - 1) f = NN - 1;   // clip (segments w/o cp gated later)
        const float4* ep = (const float4*)(emb_b + (size_t)i * DD);
        const float4* fp = (const float4*)(emb_b + (size_t)f * DD);
        float4 e0 = ep[0], e1 = ep[1];
        float4 f0 = fp[0], f1 = fp[1];
        float dx, d2 = 0.f;
        dx = e0.x - f0.x; d2 += dx * dx;
        dx = e0.y - f0.y; d2 += dx * dx;
        dx = e0.z - f0.z; d2 += dx * dx;
        dx = e0.w - f0.w; d2 += dx * dx;
        dx = e1.x - f1.x; d2 += dx * dx;
        dx = e1.y - f1.y; d2 += dx * dx;
        dx = e1.z - f1.z; d2 += dx * dx;
        dx = e1.w - f1.w; d2 += dx * dx;
        atomicAdd(&s_seg[sid], d2);
    }
    __syncthreads();

    if (t < KK) {
        g_first[b * KK + t]  = s_first[t];
        g_counts[b * KK + t] = s_counts[t];
        g_seg[b * KK + t]    = s_seg[t];
    }
}

// ---------------- kernel 2: repulsion over CP x CP pairs ---------------------
__global__ __launch_bounds__(256) void krep(
    const float* __restrict__ embed, const int* __restrict__ g_cpidx,
    const int* __restrict__ g_cpcount, float* __restrict__ g_rep)
{
    const int b  = blockIdx.x / REP_PB;
    const int pb = blockIdx.x % REP_PB;
    const int pos = g_cpcount[b];
    const float* emb_b = embed + (size_t)b * NN * DD;
    const int*   idx_b = g_cpidx + b * NN;

    int t = pb * 256 + threadIdx.x;          // 0 .. REP_PB*256-1 (16384)
    int jsplit = t & 7;                      // 8-way split of j loop
    int ti = t >> 3;                         // 0 .. 2047
    const int NI = (REP_PB * 256) / 8;       // 2048 i-threads per batch

    float sum = 0.f;
    for (int i = ti; i < pos; i += NI) {
        int ii = idx_b[i];
        const float4* ep = (const float4*)(emb_b + (size_t)ii * DD);
        float4 e0 = ep[0], e1 = ep[1];
        for (int j = jsplit; j < pos; j += 8) {
            int jj = idx_b[j];
            const float4* fp = (const float4*)(emb_b + (size_t)jj * DD);
            float4 f0 = fp[0], f1 = fp[1];
            float dx, d2 = 0.f;
            dx = e0.x - f0.x; d2 += dx * dx;
            dx = e0.y - f0.y; d2 += dx * dx;
            dx = e0.z - f0.z; d2 += dx * dx;
            dx = e0.w - f0.w; d2 += dx * dx;
            dx = e1.x - f1.x; d2 += dx * dx;
            dx = e1.y - f1.y; d2 += dx * dx;
            dx = e1.z - f1.z; d2 += dx * dx;
            dx = e1.w - f1.w; d2 += dx * dx;
            sum += __expf(-d2);
        }
    }
    #pragma unroll
    for (int o = 32; o > 0; o >>= 1) sum += __shfl_down(sum, o, 64);
    __shared__ float r[4];
    if ((threadIdx.x & 63) == 0) r[threadIdx.x >> 6] = sum;
    __syncthreads();
    if (threadIdx.x == 0)
        atomicAdd(&g_rep[b], r[0] + r[1] + r[2] + r[3]);
}

// ---------------- kernel 3: finalize (1 wave) --------------------------------
__global__ __launch_bounds__(64) void kfin(
    const int* __restrict__ g_first, const int* __restrict__ g_counts,
    const float* __restrict__ g_seg, const float* __restrict__ g_bce,
    const float* __restrict__ g_rep, const float* __restrict__ g_posf,
    float* __restrict__ out)
{
    const int k = threadIdx.x;   // 0..63
    float tot = 0.f, cnt = 0.f;
    for (int b = 0; b < BB; ++b) {
        int f   = g_first[b * KK + k];
        int c   = g_counts[b * KK + k];
        float s = g_seg[b * KK + k];
        float im = (c > 0 && f < NN) ? s / (float)c : 0.f;
        float attr = im;
        #pragma unroll
        for (int o = 32; o > 0; o >>= 1) attr += __shfl_down(attr, o, 64);
        if (k == 0) {
            float pos = g_posf[b];
            float neg = (float)NN - pos;
            bool valid = (pos >= 1.f) && (neg >= 1.f);
            float rep = (pos > 1.f) ? g_rep[b] / fmaxf(pos * pos, 1.f) : 0.f;
            float total = g_bce[b] + attr + rep;   // ATTR_W = REP_W = 1
            if (valid) { tot += total; cnt += 1.f; }
        }
    }
    if (k == 0) out[0] = (cnt > 0.f) ? tot / cnt : 0.f;
}

// ---------------- launch -----------------------------------------------------
extern "C" void kernel_launch(void* const* d_in, const int* in_sizes, int n_in,
                              void* d_out, int out_size, void* d_ws, size_t ws_size,
                              hipStream_t stream) {
    const float* beta     = (const float*)d_in[0];
    const float* embed    = (const float*)d_in[1];
    const int*   slice_id = (const int*)d_in[2];
    const int*   is_cp    = (const int*)d_in[3];
    float* out = (float*)d_out;

    // workspace layout
    int* wi = (int*)d_ws;
    int* g_first   = wi;                       // B*K
    int* g_counts  = wi + BB * KK;             // B*K
    int* g_cpcount = wi + 2 * BB * KK;         // B
    int* g_cpidx   = wi + 2 * BB * KK + BB;    // B*N
    float* wf = (float*)(wi + 17408);          // 69632-byte offset, aligned
    float* g_posf = wf;                        // B
    float* g_bce  = wf + BB;                   // B
    float* g_rep  = wf + 2 * BB;               // B
    float* g_seg  = wf + 3 * BB;               // B*K

    kstats<<<BB, 1024, 0, stream>>>(beta, embed, slice_id, is_cp,
                                    g_first, g_counts, g_cpcount, g_cpidx,
                                    g_posf, g_bce, g_rep, g_seg);
    krep<<<BB * REP_PB, 256, 0, stream>>>(embed, g_cpidx, g_cpcount, g_rep);
    kfin<<<1, 64, 0, stream>>>(g_first, g_counts, g_seg, g_bce, g_rep, g_posf, out);
}

// Round 2
// 139.368 us; speedup vs baseline: 1.6001x; 1.6001x over previous
//
#include <hip/hip_runtime.h>
#include <math.h>

#define BB 4
#define NN 4096
#define KK 64
#define ITILE 256
#define JTILE 256
#define NTI (NN / ITILE)              // 16
#define NTJ (NN / JTILE)              // 16
#define REP_BLOCKS (BB * NTI * NTJ)   // 1024

// ---------------- kernel A: per-batch stats + CP compaction ------------------
// One block per batch. Computes first_cp (segment min), counts, BCE partials,
// pos, and compacts CP embeddings (pre-scaled by sqrt(2)) + squared norms into
// workspace. Also zero-inits seg/rep/done (ws is poisoned before every call).
__global__ __launch_bounds__(1024) void kA(
    const float* __restrict__ beta, const float* __restrict__ embed,
    const int* __restrict__ sid_g, const int* __restrict__ cp_g,
    float* __restrict__ cpemb, float* __restrict__ cpsq,
    float* __restrict__ seg, float* __restrict__ bce,
    float* __restrict__ posf, float* __restrict__ rep,
    int* __restrict__ first, int* __restrict__ counts,
    int* __restrict__ cpcount, unsigned* __restrict__ done)
{
    const int b = blockIdx.x;
    const int t = threadIdx.x;
    const int lane = t & 63;

    __shared__ int s_first[KK], s_counts[KK], s_cpn;
    __shared__ float r1[16], r2[16], r3[16];

    if (t < KK) { s_first[t] = NN; s_counts[t] = 0; }
    if (t == 0) s_cpn = 0;
    __syncthreads();

    const float* beta_b = beta + (size_t)b * NN;
    const int*   sid_b  = sid_g + (size_t)b * NN;
    const int*   cp_b   = cp_g + (size_t)b * NN;
    const float* emb_b  = embed + (size_t)b * NN * 8;
    float* cpe_b = cpemb + (size_t)b * NN * 8;
    float* cpq_b = cpsq + (size_t)b * NN;

    float a1 = 0.f, a2 = 0.f;   // sum sp(-b) over y=1, sum sp(b) over y=0
    int posl = 0;

    #pragma unroll
    for (int k = 0; k < NN / 1024; ++k) {
        int i = t + k * 1024;
        int sid = sid_b[i];
        int cp  = cp_b[i];
        float bt = beta_b[i];
        // softplus(x) = max(x,0) + log(1+exp(-|x|))
        float l = __logf(1.f + __expf(-fabsf(bt)));
        bool is1 = (cp == 1);
        if (is1) {
            a1 += l + fmaxf(-bt, 0.f);
            posl++;
            atomicMin(&s_first[sid], i);
        } else {
            a2 += l + fmaxf(bt, 0.f);
        }
        atomicAdd(&s_counts[sid], 1);

        // ballot-based compaction: one LDS atomic per wave per iteration
        unsigned long long m = __ballot(is1);
        int base = 0;
        if (lane == 0) {
            int c = __popcll(m);
            if (c) base = atomicAdd(&s_cpn, c);
        }
        base = __shfl(base, 0);
        if (is1) {
            int slot = base + __popcll(m & ((1ull << lane) - 1ull));
            const float4* ep = (const float4*)(emb_b + (size_t)i * 8);
            float4 e0 = ep[0], e1 = ep[1];
            float sq = e0.x*e0.x + e0.y*e0.y + e0.z*e0.z + e0.w*e0.w
                     + e1.x*e1.x + e1.y*e1.y + e1.z*e1.z + e1.w*e1.w;
            const float S = 1.41421356237f;   // so ea_i . ea_j = 2 dot
            float4 o0 = make_float4(e0.x*S, e0.y*S, e0.z*S, e0.w*S);
            float4 o1 = make_float4(e1.x*S, e1.y*S, e1.z*S, e1.w*S);
            float4* op = (float4*)(cpe_b + (size_t)slot * 8);
            op[0] = o0; op[1] = o1;
            cpq_b[slot] = sq;
        }
    }

    // block reduction of a1, a2, pos
    float pf = (float)posl;
    #pragma unroll
    for (int o = 32; o > 0; o >>= 1) {
        a1 += __shfl_down(a1, o);
        a2 += __shfl_down(a2, o);
        pf += __shfl_down(pf, o);
    }
    int wid = t >> 6;
    if (lane == 0) { r1[wid] = a1; r2[wid] = a2; r3[wid] = pf; }
    __syncthreads();

    if (t == 0) {
        float A1 = 0.f, A2 = 0.f, P = 0.f;
        #pragma unroll
        for (int w = 0; w < 16; ++w) { A1 += r1[w]; A2 += r2[w]; P += r3[w]; }
        float neg = (float)NN - P;
        bce[b] = (neg / (P + 1e-6f) * A1 + A2) * (1.f / (float)NN);
        posf[b] = P;
        rep[b] = 0.f;
        cpcount[b] = s_cpn;
        *done = 0u;   // all 4 blocks write 0: benign
    }
    if (t < KK) {
        first[b * KK + t]  = s_first[t];
        counts[b * KK + t] = s_counts[t];
        seg[b * KK + t]    = 0.f;
    }
}

// ---------------- kernel B: attraction d2 segment sums -----------------------
// 16 blocks per batch, 256 threads, 1 element per thread. first-cp embeddings
// cached in LDS; one global atomicAdd per (block, slot).
__global__ __launch_bounds__(256) void kB(
    const float* __restrict__ embed, const int* __restrict__ sid_g,
    const int* __restrict__ first, float* __restrict__ seg)
{
    const int b   = blockIdx.x >> 4;
    const int blk = blockIdx.x & 15;
    const int t   = threadIdx.x;

    __shared__ float s_fe[KK][8];
    __shared__ float s_seg[KK];
    __shared__ int   s_f[KK];

    if (t < KK) { s_f[t] = first[b * KK + t]; s_seg[t] = 0.f; }
    __syncthreads();
    const float* emb_b = embed + (size_t)b * NN * 8;
    if (t < KK) {
        int f = s_f[t]; if (f > NN - 1) f = NN - 1;
        const float4* fp = (const float4*)(emb_b + (size_t)f * 8);
        *(float4*)&s_fe[t][0] = fp[0];
        *(float4*)&s_fe[t][4] = fp[1];
    }
    __syncthreads();

    int i = blk * 256 + t;
    int sid = sid_g[(size_t)b * NN + i];
    const float4* ep = (const float4*)(emb_b + (size_t)i * 8);
    float4 e0 = ep[0], e1 = ep[1];
    float4 f0 = *(const float4*)&s_fe[sid][0];
    float4 f1 = *(const float4*)&s_fe[sid][4];
    float dx, d2 = 0.f;
    dx = e0.x - f0.x; d2 += dx * dx;
    dx = e0.y - f0.y; d2 += dx * dx;
    dx = e0.z - f0.z; d2 += dx * dx;
    dx = e0.w - f0.w; d2 += dx * dx;
    dx = e1.x - f1.x; d2 += dx * dx;
    dx = e1.y - f1.y; d2 += dx * dx;
    dx = e1.z - f1.z; d2 += dx * dx;
    dx = e1.w - f1.w; d2 += dx * dx;
    atomicAdd(&s_seg[sid], d2);
    __syncthreads();
    if (t < KK) atomicAdd(&seg[b * KK + t], s_seg[t]);
}

// ---------------- kernel C: repulsion tiles + last-block finalize ------------
__global__ __launch_bounds__(256) void kC(
    const float* __restrict__ cpemb, const float* __restrict__ cpsq,
    const int* __restrict__ cpcount, const int* __restrict__ first,
    const int* __restrict__ counts, const float* __restrict__ seg,
    const float* __restrict__ bce, const float* __restrict__ posf,
    float* __restrict__ rep, unsigned* __restrict__ done,
    float* __restrict__ out)
{
    const int blk = blockIdx.x;
    const int b   = blk >> 8;
    const int rem = blk & 255;
    const int it  = rem >> 4;
    const int jt  = rem & 15;
    const int t   = threadIdx.x;

    __shared__ float s_je[JTILE * 8];
    __shared__ float s_jq[JTILE];
    __shared__ float r[4];
    __shared__ unsigned ticket;

    const int pos = cpcount[b];
    const bool active = (it * ITILE < pos) && (jt * JTILE < pos);

    if (active) {
        int jn = pos - jt * JTILE; if (jn > JTILE) jn = JTILE;
        const float* cpe_b = cpemb + (size_t)b * NN * 8;
        const float* cpq_b = cpsq + (size_t)b * NN;
        if (t < jn) {
            const float4* jp = (const float4*)(cpe_b + (size_t)(jt * JTILE + t) * 8);
            *(float4*)&s_je[t * 8]     = jp[0];
            *(float4*)&s_je[t * 8 + 4] = jp[1];
            s_jq[t] = cpq_b[jt * JTILE + t];
        }
        __syncthreads();

        int i = it * ITILE + t;
        bool iv = (i < pos);
        const float4* ip = (const float4*)(cpe_b + (size_t)(iv ? i : 0) * 8);
        float4 e0 = ip[0], e1 = ip[1];
        float nq = iv ? -cpq_b[i] : -1e30f;   // exp -> 0 for invalid lanes

        float sum = 0.f;
        #pragma unroll 4
        for (int j = 0; j < jn; ++j) {
            float4 f0 = *(const float4*)&s_je[j * 8];       // wave-uniform: broadcast
            float4 f1 = *(const float4*)&s_je[j * 8 + 4];
            float arg = nq - s_jq[j];
            arg = fmaf(e0.x, f0.x, arg);
            arg = fmaf(e0.y, f0.y, arg);
            arg = fmaf(e0.z, f0.z, arg);
            arg = fmaf(e0.w, f0.w, arg);
            arg = fmaf(e1.x, f1.x, arg);
            arg = fmaf(e1.y, f1.y, arg);
            arg = fmaf(e1.z, f1.z, arg);
            arg = fmaf(e1.w, f1.w, arg);
            arg = fminf(arg, 0.f);            // maximum(d2, 0)
            sum += __expf(arg);
        }
        #pragma unroll
        for (int o = 32; o > 0; o >>= 1) sum += __shfl_down(sum, o);
        if ((t & 63) == 0) r[t >> 6] = sum;
        __syncthreads();
        if (t == 0) atomicAdd(&rep[b], r[0] + r[1] + r[2] + r[3]);
    }

    // last-block ticket: rep adds are fenced before the done increment
    __threadfence();
    __syncthreads();
    if (t == 0) ticket = atomicAdd(done, 1u);
    __syncthreads();
    if (ticket == REP_BLOCKS - 1) {
        __threadfence();   // acquire all other blocks' rep adds
        if (t < 64) {
            const int k = t;
            float tot = 0.f, cnt = 0.f;
            for (int b2 = 0; b2 < BB; ++b2) {
                int f   = first[b2 * KK + k];
                int c   = counts[b2 * KK + k];
                float s = seg[b2 * KK + k];
                float attr = (c > 0 && f < NN) ? s / (float)c : 0.f;
                #pragma unroll
                for (int o = 32; o > 0; o >>= 1) attr += __shfl_down(attr, o);
                if (k == 0) {
                    float P = posf[b2];
                    float neg = (float)NN - P;
                    bool valid = (P >= 1.f) && (neg >= 1.f);
                    float rp = (P > 1.f) ? rep[b2] / fmaxf(P * P, 1.f) : 0.f;
                    float ttl = bce[b2] + attr + rp;   // ATTR_W = REP_W = 1
                    if (valid) { tot += ttl; cnt += 1.f; }
                }
            }
            if (k == 0) out[0] = (cnt > 0.f) ? tot / cnt : 0.f;
        }
    }
}

// ---------------- launch -----------------------------------------------------
extern "C" void kernel_launch(void* const* d_in, const int* in_sizes, int n_in,
                              void* d_out, int out_size, void* d_ws, size_t ws_size,
                              hipStream_t stream) {
    const float* beta     = (const float*)d_in[0];
    const float* embed    = (const float*)d_in[1];
    const int*   slice_id = (const int*)d_in[2];
    const int*   is_cp    = (const int*)d_in[3];
    float* out = (float*)d_out;

    // workspace layout (base assumed >=16B aligned)
    float* cpemb = (float*)d_ws;                 // BB*NN*8
    float* cpsq  = cpemb + (size_t)BB * NN * 8;  // BB*NN
    float* seg   = cpsq + (size_t)BB * NN;       // BB*KK
    float* bce   = seg + BB * KK;                // BB
    float* posf  = bce + BB;                     // BB
    float* rep   = posf + BB;                    // BB
    int* first   = (int*)(rep + BB);             // BB*KK
    int* counts  = first + BB * KK;              // BB*KK
    int* cpcount = counts + BB * KK;             // BB
    unsigned* done = (unsigned*)(cpcount + BB);  // 1

    kA<<<BB, 1024, 0, stream>>>(beta, embed, slice_id, is_cp,
                                cpemb, cpsq, seg, bce, posf, rep,
                                first, counts, cpcount, done);
    kB<<<BB * 16, 256, 0, stream>>>(embed, slice_id, first, seg);
    kC<<<REP_BLOCKS, 256, 0, stream>>>(cpemb, cpsq, cpcount, first, counts,
                                       seg, bce, posf, rep, done, out);
}

// Round 3
// 89.694 us; speedup vs baseline: 2.4863x; 1.5538x over previous
//
#include <hip/hip_runtime.h>
#include <math.h>

#define BB 4
#define NN 4096
#define KK 64
#define GA 8                      // kA blocks per batch
#define IT 1024                   // kC i-tile (256 thr x 4)
#define JT 32                     // kC j-tile
#define NTI (NN / IT)             // 4
#define NTJ (NN / JT)             // 128
#define KC_BLOCKS (BB * NTI * NTJ)  // 2048

// ---------------- kernel A: stats + CP compaction (8 blocks/batch) -----------
__global__ __launch_bounds__(512) void kA(
    const float* __restrict__ beta, const float* __restrict__ embed,
    const int* __restrict__ sid_g, const int* __restrict__ cp_g,
    float* __restrict__ cpemb, float* __restrict__ cpsq,
    float* __restrict__ gA1, float* __restrict__ gA2,
    float* __restrict__ gpos, int* __restrict__ gfirst,
    int* __restrict__ gcounts, int* __restrict__ cpcount)
{
    const int b   = blockIdx.x >> 3;
    const int sub = blockIdx.x & 7;
    const int t    = threadIdx.x;
    const int lane = t & 63;
    const int wid  = t >> 6;            // 8 waves

    __shared__ int   s_first[KK], s_counts[KK], s_wc[8], s_off[8], s_base;
    __shared__ float r1[8], r2[8], r3[8];

    if (t < KK) { s_first[t] = NN; s_counts[t] = 0; }
    __syncthreads();

    const int i = sub * 512 + t;
    const float* emb_b = embed + (size_t)b * NN * 8;

    int   sid = sid_g[(size_t)b * NN + i];
    int   cp  = cp_g[(size_t)b * NN + i];
    float bt  = beta[(size_t)b * NN + i];
    bool  is1 = (cp == 1);

    float l  = __logf(1.f + __expf(-fabsf(bt)));   // log(1+e^{-|x|})
    float a1 = is1 ? (l + fmaxf(-bt, 0.f)) : 0.f;  // softplus(-bt) on y=1
    float a2 = is1 ? 0.f : (l + fmaxf(bt, 0.f));   // softplus(bt) on y=0
    float pf = is1 ? 1.f : 0.f;

    if (is1) atomicMin(&s_first[sid], i);
    atomicAdd(&s_counts[sid], 1);

    unsigned long long m = __ballot(is1);
    if (lane == 0) s_wc[wid] = __popcll(m);

    #pragma unroll
    for (int o = 32; o > 0; o >>= 1) {
        a1 += __shfl_down(a1, o);
        a2 += __shfl_down(a2, o);
        pf += __shfl_down(pf, o);
    }
    if (lane == 0) { r1[wid] = a1; r2[wid] = a2; r3[wid] = pf; }
    __syncthreads();

    if (t == 0) {
        float A1 = 0.f, A2 = 0.f, P = 0.f;
        int run = 0;
        #pragma unroll
        for (int w = 0; w < 8; ++w) {
            A1 += r1[w]; A2 += r2[w]; P += r3[w];
            s_off[w] = run; run += s_wc[w];
        }
        s_base = atomicAdd(&cpcount[b], run);
        atomicAdd(&gA1[b], A1);
        atomicAdd(&gA2[b], A2);
        atomicAdd(&gpos[b], P);
    }
    __syncthreads();

    if (is1) {
        int slot = s_base + s_off[wid] + __popcll(m & ((1ull << lane) - 1ull));
        const float4* ep = (const float4*)(emb_b + (size_t)i * 8);
        float4 e0 = ep[0], e1 = ep[1];
        float sq = e0.x*e0.x + e0.y*e0.y + e0.z*e0.z + e0.w*e0.w
                 + e1.x*e1.x + e1.y*e1.y + e1.z*e1.z + e1.w*e1.w;
        const float S = 1.41421356237f;   // prescale: ea_i . ea_j = 2 dot
        float4* op = (float4*)(cpemb + ((size_t)b * NN + slot) * 8);
        op[0] = make_float4(e0.x*S, e0.y*S, e0.z*S, e0.w*S);
        op[1] = make_float4(e1.x*S, e1.y*S, e1.z*S, e1.w*S);
        cpsq[(size_t)b * NN + slot] = sq;
    }

    if (t < KK) {
        atomicMin(&gfirst[b * KK + t], s_first[t]);
        int c = s_counts[t];
        if (c) atomicAdd(&gcounts[b * KK + t], c);
    }
}

// ---------------- kernel B: attraction d2 segment sums -----------------------
__global__ __launch_bounds__(256) void kB(
    const float* __restrict__ embed, const int* __restrict__ sid_g,
    const int* __restrict__ gfirst, float* __restrict__ seg)
{
    const int b   = blockIdx.x >> 4;
    const int blk = blockIdx.x & 15;
    const int t   = threadIdx.x;

    __shared__ float s_fe[KK][8];
    __shared__ float s_seg[KK];

    const float* emb_b = embed + (size_t)b * NN * 8;
    if (t < KK) {
        s_seg[t] = 0.f;
        int f = gfirst[b * KK + t];
        if (f > NN - 1) f = NN - 1;
        const float4* fp = (const float4*)(emb_b + (size_t)f * 8);
        *(float4*)&s_fe[t][0] = fp[0];
        *(float4*)&s_fe[t][4] = fp[1];
    }
    __syncthreads();

    int i = blk * 256 + t;
    int sid = sid_g[(size_t)b * NN + i];
    const float4* ep = (const float4*)(emb_b + (size_t)i * 8);
    float4 e0 = ep[0], e1 = ep[1];
    float4 f0 = *(const float4*)&s_fe[sid][0];
    float4 f1 = *(const float4*)&s_fe[sid][4];
    float dx, d2 = 0.f;
    dx = e0.x - f0.x; d2 += dx * dx;
    dx = e0.y - f0.y; d2 += dx * dx;
    dx = e0.z - f0.z; d2 += dx * dx;
    dx = e0.w - f0.w; d2 += dx * dx;
    dx = e1.x - f1.x; d2 += dx * dx;
    dx = e1.y - f1.y; d2 += dx * dx;
    dx = e1.z - f1.z; d2 += dx * dx;
    dx = e1.w - f1.w; d2 += dx * dx;
    atomicAdd(&s_seg[sid], d2);
    __syncthreads();
    if (t < KK) atomicAdd(&seg[b * KK + t], s_seg[t]);
}

// ---------------- kernel C: repulsion tiles (4 i per thread) -----------------
__global__ __launch_bounds__(256) void kC(
    const float* __restrict__ cpemb, const float* __restrict__ cpsq,
    const int* __restrict__ cpcount, float* __restrict__ rep)
{
    const int blk = blockIdx.x;
    const int b   = blk >> 9;
    const int rem = blk & 511;
    const int it  = rem >> 7;     // 0..3
    const int jt  = rem & 127;    // 0..127
    const int t   = threadIdx.x;

    const int pos = cpcount[b];
    if (it * IT >= pos || jt * JT >= pos) return;   // block-uniform exit

    __shared__ float s_je[JT * 8];
    __shared__ float s_jq[JT];
    __shared__ float r[4];

    int jn = pos - jt * JT; if (jn > JT) jn = JT;
    const float* cpe_b = cpemb + (size_t)b * NN * 8;
    const float* cpq_b = cpsq + (size_t)b * NN;

    if (t < 64) {   // 32 rows x 2 float4
        int row = t >> 1, half = t & 1;
        if (row < jn) {
            *(float4*)&s_je[row * 8 + half * 4] =
                *(const float4*)(cpe_b + (size_t)(jt * JT + row) * 8 + half * 4);
            if (half == 0) s_jq[row] = cpq_b[jt * JT + row];
        }
    }
    __syncthreads();

    // 4 i's per thread
    float4 e0[4], e1[4];
    float  nq[4];
    #pragma unroll
    for (int u = 0; u < 4; ++u) {
        int i = it * IT + u * 256 + t;
        bool iv = (i < pos);
        const float4* ip = (const float4*)(cpe_b + (size_t)(iv ? i : 0) * 8);
        e0[u] = ip[0]; e1[u] = ip[1];
        nq[u] = iv ? -cpq_b[i] : -1e30f;   // exp -> 0 for invalid lanes
    }

    float sum = 0.f;
    #pragma unroll 2
    for (int j = 0; j < jn; ++j) {
        float4 f0 = *(const float4*)&s_je[j * 8];       // wave-uniform broadcast
        float4 f1 = *(const float4*)&s_je[j * 8 + 4];
        float qj = s_jq[j];
        #pragma unroll
        for (int u = 0; u < 4; ++u) {
            float arg = nq[u] - qj;
            arg = fmaf(e0[u].x, f0.x, arg);
            arg = fmaf(e0[u].y, f0.y, arg);
            arg = fmaf(e0[u].z, f0.z, arg);
            arg = fmaf(e0[u].w, f0.w, arg);
            arg = fmaf(e1[u].x, f1.x, arg);
            arg = fmaf(e1[u].y, f1.y, arg);
            arg = fmaf(e1[u].z, f1.z, arg);
            arg = fmaf(e1[u].w, f1.w, arg);
            arg = fminf(arg, 0.f);          // maximum(d2, 0)
            sum += __expf(arg);
        }
    }
    #pragma unroll
    for (int o = 32; o > 0; o >>= 1) sum += __shfl_down(sum, o);
    if ((t & 63) == 0) r[t >> 6] = sum;
    __syncthreads();
    if (t == 0) atomicAdd(&rep[b], r[0] + r[1] + r[2] + r[3]);
}

// ---------------- kernel D: finalize (1 wave) --------------------------------
__global__ __launch_bounds__(64) void kD(
    const int* __restrict__ gfirst, const int* __restrict__ gcounts,
    const float* __restrict__ seg, const float* __restrict__ gA1,
    const float* __restrict__ gA2, const float* __restrict__ gpos,
    const float* __restrict__ rep, float* __restrict__ out)
{
    const int k = threadIdx.x;
    float tot = 0.f, cnt = 0.f;
    for (int b = 0; b < BB; ++b) {
        int f   = gfirst[b * KK + k];
        int c   = gcounts[b * KK + k];
        float s = seg[b * KK + k];
        float attr = (c > 0 && f < NN) ? s / (float)c : 0.f;
        #pragma unroll
        for (int o = 32; o > 0; o >>= 1) attr += __shfl_down(attr, o);
        if (k == 0) {
            float P = gpos[b];
            float neg = (float)NN - P;
            bool valid = (P >= 1.f) && (neg >= 1.f);
            float bce = (neg / (P + 1e-6f) * gA1[b] + gA2[b]) * (1.f / (float)NN);
            float rp = (P > 1.f) ? rep[b] / fmaxf(P * P, 1.f) : 0.f;
            float ttl = bce + attr + rp;    // ATTR_W = REP_W = 1
            if (valid) { tot += ttl; cnt += 1.f; }
        }
    }
    if (k == 0) out[0] = (cnt > 0.f) ? tot / cnt : 0.f;
}

// ---------------- launch -----------------------------------------------------
extern "C" void kernel_launch(void* const* d_in, const int* in_sizes, int n_in,
                              void* d_out, int out_size, void* d_ws, size_t ws_size,
                              hipStream_t stream) {
    const float* beta     = (const float*)d_in[0];
    const float* embed    = (const float*)d_in[1];
    const int*   slice_id = (const int*)d_in[2];
    const int*   is_cp    = (const int*)d_in[3];
    float* out = (float*)d_out;

    // workspace layout
    float* cpemb = (float*)d_ws;                  // B*N*8
    float* cpsq  = cpemb + (size_t)BB * NN * 8;   // B*N
    // --- zero region (one memset) ---
    float* gA1   = cpsq + (size_t)BB * NN;        // B
    float* gA2   = gA1 + BB;                      // B
    float* gpos  = gA2 + BB;                      // B
    float* rep   = gpos + BB;                     // B
    float* seg   = rep + BB;                      // B*K
    int* gcounts = (int*)(seg + BB * KK);         // B*K
    int* cpcount = gcounts + BB * KK;             // B
    // --- 0x7f region (one memset) ---
    int* gfirst  = cpcount + BB;                  // B*K

    size_t zero_bytes = (size_t)(4 * BB + 2 * BB * KK + BB) * 4;  // 2128 B
    hipMemsetAsync(gA1, 0, zero_bytes, stream);
    hipMemsetAsync(gfirst, 0x7F, BB * KK * 4, stream);

    kA<<<BB * GA, 512, 0, stream>>>(beta, embed, slice_id, is_cp,
                                    cpemb, cpsq, gA1, gA2, gpos,
                                    gfirst, gcounts, cpcount);
    kB<<<BB * 16, 256, 0, stream>>>(embed, slice_id, gfirst, seg);
    kC<<<KC_BLOCKS, 256, 0, stream>>>(cpemb, cpsq, cpcount, rep);
    kD<<<1, 64, 0, stream>>>(gfirst, gcounts, seg, gA1, gA2, gpos, rep, out);
}